// Round 10
// baseline (2546.246 us; speedup 1.0000x reference)
//
#include <hip/hip_runtime.h>
#include <hip/hip_bf16.h>

#define B_TOT 1024
#define T_STEPS 128
#define N_NODES 5
#define FML 32
#define IN_F 165     // 5 + 160
#define F1 256
#define F2 256
#define F3 512
#define NCLS 7
#define BM 64        // batch rows per block (4 MFMA row-tiles)
#define NRT 4        // row tiles
#define BMH 8        // rows per block in head kernel

typedef __attribute__((ext_vector_type(8))) short bfrag;   // 8 bf16 (4 VGPRs)
typedef __attribute__((ext_vector_type(4))) float f32x4;

#define MFMA16 __builtin_amdgcn_mfma_f32_16x16x32_bf16

// p1 per-node layout (bf16 elems): kt<5 frags [(kt*16+ct)*64+lane]*8 = 40960,
// then dense x-part [(ct*16+c16)*8] = 2048 -> node stride 43008 (r7-validated).
#define P1_NODE 43008
#define P1_XOFF 40960
#define L2_FRAGS 128              // 8 kt x 16 ct
#define P2_NODE (L2_FRAGS * 64 * 8)
#define L3_FRAGS 16               // 8 kt x 2 ct
#define P3_NODE (L3_FRAGS * 64 * 8)

#define INP_STRIDE 200   // bf16: [state 0..159 | x 160..164 | zero pad..199]
#define H_STRIDE 264

__device__ __forceinline__ __hip_bfloat16 tobf(float v) { return __float2bfloat16(v); }

// ---------------- Kernel 0: pack weights (r7-validated layout) ----------------
__global__ __launch_bounds__(256) void pack_weights(
    const float* __restrict__ Wf1, const float* __restrict__ Wf2, const float* __restrict__ Wf3,
    __hip_bfloat16* __restrict__ p1, __hip_bfloat16* __restrict__ p2, __hip_bfloat16* __restrict__ p3) {
  const int stride = gridDim.x * 256;
  for (int it = blockIdx.x * 256 + threadIdx.x; it < N_NODES * 14592; it += stride) {
    int node = it / 14592, u = it % 14592;
    if (u < 5120) {                 // L1 main: k' 0..159 -> W rows 5..164 (state)
      int lane = u & 63, frag = u >> 6;
      int kt = frag >> 4, ct = frag & 15;
      int g = lane >> 4, c16 = lane & 15;
      __hip_bfloat16* dst = p1 + (size_t)node * P1_NODE + (size_t)u * 8;
      const float* W = Wf1 + (size_t)node * IN_F * F1;
#pragma unroll
      for (int e = 0; e < 8; ++e) {
        int k = kt * 32 + g * 8 + e;
        dst[e] = tobf(W[(size_t)(5 + k) * F1 + ct * 16 + c16]);
      }
    } else if (u < 5376) {          // L1 x-part (dense): W rows 0..4 then 0
      int v = u - 5120;
      int ct = v >> 4, c16 = v & 15;
      __hip_bfloat16* dst = p1 + (size_t)node * P1_NODE + P1_XOFF + (size_t)v * 8;
      const float* W = Wf1 + (size_t)node * IN_F * F1;
#pragma unroll
      for (int e = 0; e < 8; ++e)
        dst[e] = (e < 5) ? tobf(W[(size_t)e * F1 + ct * 16 + c16]) : tobf(0.f);
    } else if (u < 5376 + 8192) {   // L2
      int v = u - 5376;
      int lane = v & 63, frag = v >> 6;
      int kt = frag >> 4, ct = frag & 15;
      int g = lane >> 4, c16 = lane & 15;
      __hip_bfloat16* dst = p2 + (size_t)node * P2_NODE + (size_t)v * 8;
      const float* W = Wf2 + (size_t)node * F1 * F2;
#pragma unroll
      for (int e = 0; e < 8; ++e) {
        int k = kt * 32 + g * 8 + e;
        dst[e] = tobf(W[(size_t)k * F2 + ct * 16 + c16]);
      }
    } else {                        // L3: frag = kt*2 + ct
      int v = u - 13568;
      int lane = v & 63, frag = v >> 6;
      int kt = frag >> 1, ct = frag & 1;
      int g = lane >> 4, c16 = lane & 15;
      __hip_bfloat16* dst = p3 + (size_t)node * P3_NODE + (size_t)v * 8;
      const float* W = Wf3 + (size_t)node * F2 * FML;
#pragma unroll
      for (int e = 0; e < 8; ++e) {
        int k = kt * 32 + g * 8 + e;
        dst[e] = tobf(W[(size_t)k * FML + ct * 16 + c16]);
      }
    }
  }
}

// relu + bias + pack 4 fp32 -> 4 bf16 -> one 8B LDS write
__device__ __forceinline__ void relu_pack_store(__hip_bfloat16* p, f32x4 acc, float4 b) {
  union { ushort4 v; __hip_bfloat16 h[4]; } u;
  u.h[0] = tobf(fmaxf(acc[0] + b.x, 0.f));
  u.h[1] = tobf(fmaxf(acc[1] + b.y, 0.f));
  u.h[2] = tobf(fmaxf(acc[2] + b.z, 0.f));
  u.h[3] = tobf(fmaxf(acc[3] + b.w, 0.f));
  *reinterpret_cast<ushort4*>(p) = u.v;
}

// ---------------- Kernel 1: persistent recurrence, BM=64 (4 row-tiles) ----------------
// 16 blocks x 512 threads (8 waves). Block owns rows [b*64, b*64+64).
// A = weights (M = out-channels), B = activations (N = batch rows).
// D: outc = (lane>>4)*4 + reg, batch = lane&15.
// Same weight bytes per update as the 1463µs r4 kernel, but 4x the rows ->
// per-phase compute (48-64 MFMA/wave) now covers the L2->CU port drain
// (~128KB/phase). Phase C: wave pair (2rt,2rt+1) does row-tile rt's L3.
__global__ __launch_bounds__(512, 2) void recur_kernel(
    const float* __restrict__ x,
    const __hip_bfloat16* __restrict__ p1, const float* __restrict__ bf1,
    const __hip_bfloat16* __restrict__ p2, const float* __restrict__ bf2,
    const __hip_bfloat16* __restrict__ p3, const float* __restrict__ bf3,
    float* __restrict__ feat_out) {
  __shared__ __align__(16) __hip_bfloat16 inp_s[BM][INP_STRIDE];   // 25.6 KiB
  __shared__ __align__(16) __hip_bfloat16 h1_s[BM][H_STRIDE];     // 33.8 KiB
  __shared__ __align__(16) __hip_bfloat16 h2_s[BM][H_STRIDE];     // 33.8 KiB

  const int tid = threadIdx.x;
  const int lane = tid & 63;
  const int w = tid >> 6;          // wave 0..7
  const int g = lane >> 4;
  const int c16 = lane & 15;
  const int ct0 = 2 * w, ct1 = 2 * w + 1;
  const int r0 = blockIdx.x * BM;

  const bfrag* Pf1 = (const bfrag*)p1;
  const bfrag* Pf2 = (const bfrag*)p2;
  const bfrag* Pf3 = (const bfrag*)p3;

  // zero state + pads
  for (int idx = tid; idx < BM * INP_STRIDE; idx += 512)
    ((__hip_bfloat16*)inp_s)[idx] = tobf(0.f);
  __syncthreads();
  // x_0 -> cols 160..164 (320 values)
  if (tid < BM * N_NODES) {
    int r = tid / N_NODES, n = tid % N_NODES;
    inp_s[r][160 + n] = tobf(x[(size_t)(r0 + r) * (N_NODES * T_STEPS) + n * T_STEPS]);
  }
  __syncthreads();

  // preload node-0 L1 weights: 2 ct x (5 main frags + dense x frag, g==0 lanes)
  bfrag wL1[2][5], wL1x[2];
#pragma unroll
  for (int kt = 0; kt < 5; ++kt) {
    wL1[0][kt] = Pf1[(kt * 16 + ct0) * 64 + lane];
    wL1[1][kt] = Pf1[(kt * 16 + ct1) * 64 + lane];
  }
  {
    bfrag z = {0,0,0,0,0,0,0,0};
    wL1x[0] = (g == 0) ? Pf1[P1_XOFF / 8 + ct0 * 16 + c16] : z;
    wL1x[1] = (g == 0) ? Pf1[P1_XOFF / 8 + ct1 * 16 + c16] : z;
  }

#pragma unroll 1
  for (int t = 0; t < T_STEPS; ++t) {
#pragma unroll 1
    for (int i = 0; i < N_NODES; ++i) {
      const int inext = (i + 1 == N_NODES) ? 0 : i + 1;

      // ================= PHASE A: layer 1, 4 row-tiles (48 MFMA/wave) =================
      // issue this node's L2 weights (consumed in PHASE B; drain hides under A)
      bfrag w2[2][8];
      {
        const bfrag* P = Pf2 + (size_t)i * L2_FRAGS * 64;
#pragma unroll
        for (int kt = 0; kt < 8; ++kt) {
          w2[0][kt] = P[(kt * 16 + ct0) * 64 + lane];
          w2[1][kt] = P[(kt * 16 + ct1) * 64 + lane];
        }
      }
      {
        float4 biA0 = *(const float4*)&bf1[i * F1 + ct0 * 16 + 4 * g];
        float4 biA1 = *(const float4*)&bf1[i * F1 + ct1 * 16 + 4 * g];
#pragma unroll
        for (int rt = 0; rt < NRT; ++rt) {
          const int row = rt * 16 + c16;
          bfrag a[5], a5;
#pragma unroll
          for (int kt = 0; kt < 5; ++kt)
            a[kt] = *(const bfrag*)&inp_s[row][kt * 32 + g * 8];
          a5 = *(const bfrag*)&inp_s[row][160 + g * 8];
          f32x4 acc0 = {0.f,0.f,0.f,0.f}, acc1 = {0.f,0.f,0.f,0.f};
          f32x4 acc0b = {0.f,0.f,0.f,0.f}, acc1b = {0.f,0.f,0.f,0.f};
#pragma unroll
          for (int kt = 0; kt < 2; ++kt) {
            acc0  = MFMA16(wL1[0][kt],     a[kt],     acc0,  0, 0, 0);
            acc1  = MFMA16(wL1[1][kt],     a[kt],     acc1,  0, 0, 0);
            acc0b = MFMA16(wL1[0][kt + 2], a[kt + 2], acc0b, 0, 0, 0);
            acc1b = MFMA16(wL1[1][kt + 2], a[kt + 2], acc1b, 0, 0, 0);
          }
          acc0  = MFMA16(wL1[0][4], a[4], acc0,  0, 0, 0);
          acc1  = MFMA16(wL1[1][4], a[4], acc1,  0, 0, 0);
          acc0b = MFMA16(wL1x[0],   a5,   acc0b, 0, 0, 0);
          acc1b = MFMA16(wL1x[1],   a5,   acc1b, 0, 0, 0);
          acc0 += acc0b; acc1 += acc1b;
          relu_pack_store(&h1_s[row][ct0 * 16 + 4 * g], acc0, biA0);
          relu_pack_store(&h1_s[row][ct1 * 16 + 4 * g], acc1, biA1);
        }
      }
      __syncthreads();

      // ================= PHASE B: layer 2, 4 row-tiles (64 MFMA/wave) =================
      // issue next node's L1 weights (consumed after rotate at phase C end)
      bfrag w1n[2][5], w1nx[2];
      {
        const bfrag* P = Pf1 + (size_t)inext * (P1_NODE / 8);
#pragma unroll
        for (int kt = 0; kt < 5; ++kt) {
          w1n[0][kt] = P[(kt * 16 + ct0) * 64 + lane];
          w1n[1][kt] = P[(kt * 16 + ct1) * 64 + lane];
        }
        bfrag z = {0,0,0,0,0,0,0,0};
        w1nx[0] = (g == 0) ? P[P1_XOFF / 8 + ct0 * 16 + c16] : z;
        w1nx[1] = (g == 0) ? P[P1_XOFF / 8 + ct1 * 16 + c16] : z;
      }
      // issue x_{t+1} (committed in PHASE C of i==4)
      float xv = 0.f;
      if (i == 4 && tid < BM * N_NODES && t + 1 < T_STEPS)
        xv = x[(size_t)(r0 + tid / N_NODES) * (N_NODES * T_STEPS) +
               (tid % N_NODES) * T_STEPS + (t + 1)];
      {
        float4 biB0 = *(const float4*)&bf2[i * F2 + ct0 * 16 + 4 * g];
        float4 biB1 = *(const float4*)&bf2[i * F2 + ct1 * 16 + 4 * g];
#pragma unroll
        for (int rt = 0; rt < NRT; ++rt) {
          const int row = rt * 16 + c16;
          bfrag ab[8];
#pragma unroll
          for (int kt = 0; kt < 8; ++kt)
            ab[kt] = *(const bfrag*)&h1_s[row][kt * 32 + g * 8];
          f32x4 acc0 = {0.f,0.f,0.f,0.f}, acc1 = {0.f,0.f,0.f,0.f};
          f32x4 acc0b = {0.f,0.f,0.f,0.f}, acc1b = {0.f,0.f,0.f,0.f};
#pragma unroll
          for (int kt = 0; kt < 4; ++kt) {
            acc0  = MFMA16(w2[0][kt],     ab[kt],     acc0,  0, 0, 0);
            acc1  = MFMA16(w2[1][kt],     ab[kt],     acc1,  0, 0, 0);
            acc0b = MFMA16(w2[0][kt + 4], ab[kt + 4], acc0b, 0, 0, 0);
            acc1b = MFMA16(w2[1][kt + 4], ab[kt + 4], acc1b, 0, 0, 0);
          }
          acc0 += acc0b; acc1 += acc1b;
          relu_pack_store(&h2_s[row][ct0 * 16 + 4 * g], acc0, biB0);
          relu_pack_store(&h2_s[row][ct1 * 16 + 4 * g], acc1, biB1);
        }
      }
      __syncthreads();

      // ================= PHASE C: layer 3, wave pair per row-tile =================
      {
        // wave w: row-tile rt = w>>1, state-col half ctc = w&1
        const int rt = w >> 1, ctc = w & 1;
        const int row = rt * 16 + c16;
        bfrag w3[8];
        {
          const bfrag* P = Pf3 + (size_t)i * L3_FRAGS * 64;
#pragma unroll
          for (int kt = 0; kt < 8; ++kt)
            w3[kt] = P[(kt * 2 + ctc) * 64 + lane];   // duplicates across wave pairs hit L1
        }
        bfrag ac[8];
#pragma unroll
        for (int kt = 0; kt < 8; ++kt)
          ac[kt] = *(const bfrag*)&h2_s[row][kt * 32 + g * 8];
        f32x4 acc = {0.f,0.f,0.f,0.f}, accb = {0.f,0.f,0.f,0.f};
#pragma unroll
        for (int kt = 0; kt < 4; ++kt) {
          acc  = MFMA16(w3[kt],     ac[kt],     acc,  0, 0, 0);
          accb = MFMA16(w3[kt + 4], ac[kt + 4], accb, 0, 0, 0);
        }
        acc += accb;
        const int sc = i * FML + ctc * 16 + 4 * g;   // state col base (0..159)
        float4 bic = *(const float4*)&bf3[sc];
        union { ushort4 v; __hip_bfloat16 h[4]; } u;
        float vs[4];
#pragma unroll
        for (int e = 0; e < 4; ++e) {
          vs[e] = fmaxf(acc[e] + ((const float*)&bic)[e], 0.f);
          u.h[e] = tobf(vs[e]);
        }
        *reinterpret_cast<ushort4*>(&inp_s[row][sc]) = u.v;   // Gauss-Seidel update
        if (t == T_STEPS - 1) {
#pragma unroll
          for (int e = 0; e < 4; ++e)
            feat_out[(size_t)(r0 + row) * IN_F + 5 + sc + e] = vs[e];  // fp32 for head
        }
      }
      // commit x_{t+1} (cols 160-164; disjoint from slice writes above)
      if (i == 4 && tid < BM * N_NODES && t + 1 < T_STEPS)
        inp_s[tid / N_NODES][160 + tid % N_NODES] = tobf(xv);
      __syncthreads();

      // rotate next-node L1 weights in
#pragma unroll
      for (int kt = 0; kt < 5; ++kt) {
        wL1[0][kt] = w1n[0][kt];
        wL1[1][kt] = w1n[1][kt];
      }
      wL1x[0] = w1nx[0];
      wL1x[1] = w1nx[1];
    }
  }

  // feat x-part (fp32, exact)
  if (tid < BM * N_NODES) {
    int r = tid / N_NODES, n = tid % N_NODES;
    feat_out[(size_t)(r0 + r) * IN_F + n] =
        x[(size_t)(r0 + r) * (N_NODES * T_STEPS) + n * T_STEPS + (T_STEPS - 1)];
  }
}

// ---------------- Kernel 2: head layer 1 (feat @ Wo1 + bo1, ReLU) ----------------
__global__ __launch_bounds__(256) void head1_kernel(
    const float* __restrict__ feat, const float* __restrict__ Wo1,
    const float* __restrict__ bo1, float* __restrict__ H) {
  __shared__ __align__(16) float f[BMH][168];
  const int tid = threadIdx.x;
  const int r0 = blockIdx.x * BMH;
  for (int idx = tid; idx < BMH * 168; idx += 256) {
    int r = idx / 168, c = idx % 168;
    f[r][c] = (c < IN_F) ? feat[(size_t)(r0 + r) * IN_F + c] : 0.f;
  }
  __syncthreads();
  const int c0 = tid, c1 = tid + 256;
  float acc0[BMH], acc1[BMH];
#pragma unroll
  for (int r = 0; r < BMH; ++r) { acc0[r] = 0.f; acc1[r] = 0.f; }
  int k = 0;
  for (; k + 3 < IN_F; k += 4) {
    float w00 = Wo1[(k + 0) * F3 + c0], w01 = Wo1[(k + 0) * F3 + c1];
    float w10 = Wo1[(k + 1) * F3 + c0], w11 = Wo1[(k + 1) * F3 + c1];
    float w20 = Wo1[(k + 2) * F3 + c0], w21 = Wo1[(k + 2) * F3 + c1];
    float w30 = Wo1[(k + 3) * F3 + c0], w31 = Wo1[(k + 3) * F3 + c1];
#pragma unroll
    for (int r = 0; r < BMH; ++r) {
      float4 v = *reinterpret_cast<const float4*>(&f[r][k]);
      acc0[r] = fmaf(v.x, w00, acc0[r]); acc1[r] = fmaf(v.x, w01, acc1[r]);
      acc0[r] = fmaf(v.y, w10, acc0[r]); acc1[r] = fmaf(v.y, w11, acc1[r]);
      acc0[r] = fmaf(v.z, w20, acc0[r]); acc1[r] = fmaf(v.z, w21, acc1[r]);
      acc0[r] = fmaf(v.w, w30, acc0[r]); acc1[r] = fmaf(v.w, w31, acc1[r]);
    }
  }
  {
    float w0 = Wo1[164 * F3 + c0], w1 = Wo1[164 * F3 + c1];
#pragma unroll
    for (int r = 0; r < BMH; ++r) {
      acc0[r] = fmaf(f[r][164], w0, acc0[r]);
      acc1[r] = fmaf(f[r][164], w1, acc1[r]);
    }
  }
  float b0 = bo1[c0], b1 = bo1[c1];
#pragma unroll
  for (int r = 0; r < BMH; ++r) {
    H[(size_t)(r0 + r) * F3 + c0] = fmaxf(acc0[r] + b0, 0.f);
    H[(size_t)(r0 + r) * F3 + c1] = fmaxf(acc1[r] + b1, 0.f);
  }
}

// ---------------- Kernel 3: BN stats -> per-column scale/shift ----------------
__global__ __launch_bounds__(256) void bn_stats_kernel(
    const float* __restrict__ H, const float* __restrict__ gamma,
    const float* __restrict__ beta, float* __restrict__ ab) {
  const int c = blockIdx.x;
  const int tid = threadIdx.x;
  float sm = 0.f, q = 0.f;
  for (int r = tid; r < B_TOT; r += 256) {
    float v = H[(size_t)r * F3 + c];
    sm += v; q += v * v;
  }
  __shared__ float ls[256], lq[256];
  ls[tid] = sm; lq[tid] = q;
  __syncthreads();
  for (int off = 128; off; off >>= 1) {
    if (tid < off) { ls[tid] += ls[tid + off]; lq[tid] += lq[tid + off]; }
    __syncthreads();
  }
  if (tid == 0) {
    float mu = ls[0] * (1.f / B_TOT);
    float var = lq[0] * (1.f / B_TOT) - mu * mu;
    float inv = rsqrtf(var + 1e-5f);
    float a = gamma[c] * inv;
    ab[c] = a;
    ab[F3 + c] = beta[c] - mu * a;
  }
}

// ---------------- Kernel 4: logits + softmax (1 wave per row) ----------------
__global__ __launch_bounds__(256) void out_kernel(
    const float* __restrict__ H, const float* __restrict__ ab,
    const float* __restrict__ Wo2, const float* __restrict__ bo2,
    float* __restrict__ out) {
  const int wid = threadIdx.x >> 6, lane = threadIdx.x & 63;
  const int r = blockIdx.x * 4 + wid;
  float acc[NCLS];
#pragma unroll
  for (int j = 0; j < NCLS; ++j) acc[j] = 0.f;
  for (int k = lane; k < F3; k += 64) {
    float hv = H[(size_t)r * F3 + k] * ab[k] + ab[F3 + k];
#pragma unroll
    for (int j = 0; j < NCLS; ++j) acc[j] = fmaf(hv, Wo2[k * NCLS + j], acc[j]);
  }
#pragma unroll
  for (int j = 0; j < NCLS; ++j)
    for (int off = 32; off; off >>= 1) acc[j] += __shfl_xor(acc[j], off);
  if (lane == 0) {
    float lg[NCLS], mx = -1e30f;
#pragma unroll
    for (int j = 0; j < NCLS; ++j) { lg[j] = acc[j] + bo2[j]; mx = fmaxf(mx, lg[j]); }
    float sum = 0.f;
#pragma unroll
    for (int j = 0; j < NCLS; ++j) { lg[j] = __expf(lg[j] - mx); sum += lg[j]; }
    float inv = 1.f / sum;
#pragma unroll
    for (int j = 0; j < NCLS; ++j) out[(size_t)r * NCLS + j] = lg[j] * inv;
  }
}

extern "C" void kernel_launch(void* const* d_in, const int* in_sizes, int n_in,
                              void* d_out, int out_size, void* d_ws, size_t ws_size,
                              hipStream_t stream) {
  const float* x   = (const float*)d_in[0];
  const float* Wf1 = (const float*)d_in[1];
  const float* bf1 = (const float*)d_in[2];
  const float* Wf2 = (const float*)d_in[3];
  const float* bf2 = (const float*)d_in[4];
  const float* Wf3 = (const float*)d_in[5];
  const float* bf3 = (const float*)d_in[6];
  const float* Wo1 = (const float*)d_in[7];
  const float* bo1 = (const float*)d_in[8];
  const float* gamma = (const float*)d_in[9];
  const float* beta  = (const float*)d_in[10];
  const float* Wo2 = (const float*)d_in[11];
  const float* bo2 = (const float*)d_in[12];
  float* out = (float*)d_out;

  char* ws = (char*)d_ws;
  size_t off = 0;
  __hip_bfloat16* p1 = (__hip_bfloat16*)(ws + off); off += (size_t)N_NODES * P1_NODE * 2;
  __hip_bfloat16* p2 = (__hip_bfloat16*)(ws + off); off += (size_t)N_NODES * P2_NODE * 2;
  __hip_bfloat16* p3 = (__hip_bfloat16*)(ws + off); off += (size_t)N_NODES * P3_NODE * 2;
  float* feat = (float*)(ws + off); off += (size_t)B_TOT * IN_F * 4;
  float* H    = (float*)(ws + off); off += (size_t)B_TOT * F3 * 4;
  float* ab   = (float*)(ws + off); off += 2 * F3 * 4;

  pack_weights<<<285, 256, 0, stream>>>(Wf1, Wf2, Wf3, p1, p2, p3);
  recur_kernel<<<B_TOT / BM, 512, 0, stream>>>(x, p1, bf1, p2, bf2, p3, bf3, feat);
  head1_kernel<<<B_TOT / BMH, 256, 0, stream>>>(feat, Wo1, bo1, H);
  bn_stats_kernel<<<F3, 256, 0, stream>>>(H, gamma, beta, ab);
  out_kernel<<<B_TOT / 4, 256, 0, stream>>>(H, ab, Wo2, bo2, out);
}

// Round 11
// 1461.288 us; speedup vs baseline: 1.7425x; 1.7425x over previous
//
#include <hip/hip_runtime.h>
#include <hip/hip_bf16.h>

#define B_TOT 1024
#define T_STEPS 128
#define N_NODES 5
#define FML 32
#define IN_F 165     // 5 + 160
#define F1 256
#define F2 256
#define F3 512
#define NCLS 7
#define BM 16        // batch rows per block in recurrence (MFMA N)
#define BMH 8        // rows per block in head kernel

typedef __attribute__((ext_vector_type(8))) short bfrag;   // 8 bf16 (4 VGPRs)
typedef __attribute__((ext_vector_type(4))) float f32x4;

#define MFMA16 __builtin_amdgcn_mfma_f32_16x16x32_bf16

// Packed fragment counts per node
#define L1_KT 6      // K padded: 192 packed features = [state 160 | x 5 | zero 27]
#define L1_CT 16
#define L2_KT 8
#define L2_CT 16
#define L3_KT 8
#define L3_CT 2
#define L1_FRAGS (L1_KT * L1_CT)   // 96
#define L2_FRAGS (L2_KT * L2_CT)   // 128
#define L3_FRAGS (L3_KT * L3_CT)   // 16

#define INP_STRIDE 200   // bf16 elems: [state 0..159 | x 160..164 | pad..199]
#define H_STRIDE 264

__device__ __forceinline__ __hip_bfloat16 tobf(float v) { return __float2bfloat16(v); }

// ---------------- Kernel 0: pack weights into MFMA A-fragment layout (bf16) ----------------
// frag elem (lane,e) = W[k = kt*32 + (lane>>4)*8 + e][ct*16 + (lane&15)]
// For Wf1, the packed feature index k' is permuted: k'<160 -> W row 5+k' (state),
// 160<=k'<165 -> W row k'-160 (x), else zero pad.
__global__ __launch_bounds__(256) void pack_weights(
    const float* __restrict__ Wf1, const float* __restrict__ Wf2, const float* __restrict__ Wf3,
    __hip_bfloat16* __restrict__ p1, __hip_bfloat16* __restrict__ p2, __hip_bfloat16* __restrict__ p3) {
  int tid = blockIdx.x * 256 + threadIdx.x;   // total 5*240*64 = 76800
  int node = tid / (240 * 64);
  int rem  = tid % (240 * 64);
  int frag = rem >> 6;
  int lane = rem & 63;
  int g = lane >> 4, c16 = lane & 15;
  if (frag < L1_FRAGS) {
    int kt = frag / L1_CT, ct = frag % L1_CT;
    __hip_bfloat16* dst = p1 + (((size_t)node * L1_FRAGS + frag) * 64 + lane) * 8;
    const float* W = Wf1 + (size_t)node * IN_F * F1;
#pragma unroll
    for (int e = 0; e < 8; ++e) {
      int k = kt * 32 + g * 8 + e;                      // packed feature index
      int row = (k < 160) ? (5 + k) : ((k < IN_F) ? (k - 160) : -1);
      float v = (row >= 0) ? W[(size_t)row * F1 + ct * 16 + c16] : 0.f;
      dst[e] = tobf(v);
    }
  } else if (frag < L1_FRAGS + L2_FRAGS) {
    int f = frag - L1_FRAGS;
    __hip_bfloat16* dst = p2 + (((size_t)node * L2_FRAGS + f) * 64 + lane) * 8;
    const float* W = Wf2 + (size_t)node * F1 * F2;
    int kt = f / L2_CT, ct = f % L2_CT;
#pragma unroll
    for (int e = 0; e < 8; ++e) {
      int k = kt * 32 + g * 8 + e;
      dst[e] = tobf(W[(size_t)k * F2 + ct * 16 + c16]);
    }
  } else {
    int f = frag - L1_FRAGS - L2_FRAGS;
    __hip_bfloat16* dst = p3 + (((size_t)node * L3_FRAGS + f) * 64 + lane) * 8;
    const float* W = Wf3 + (size_t)node * F2 * FML;
    int kt = f / L3_CT, ct = f % L3_CT;
#pragma unroll
    for (int e = 0; e < 8; ++e) {
      int k = kt * 32 + g * 8 + e;
      dst[e] = tobf(W[(size_t)k * FML + ct * 16 + c16]);
    }
  }
}

// relu + bias + pack 4 fp32 -> 4 bf16 -> one 8B LDS write
__device__ __forceinline__ void relu_pack_store(__hip_bfloat16* p, f32x4 acc, float4 b) {
  union { ushort4 v; __hip_bfloat16 h[4]; } u;
  u.h[0] = tobf(fmaxf(acc[0] + b.x, 0.f));
  u.h[1] = tobf(fmaxf(acc[1] + b.y, 0.f));
  u.h[2] = tobf(fmaxf(acc[2] + b.z, 0.f));
  u.h[3] = tobf(fmaxf(acc[3] + b.w, 0.f));
  *reinterpret_cast<ushort4*>(p) = u.v;
}

// ---------------- Kernel 1: persistent recurrence, one-phase-ahead prefetch ----------------
// 64 blocks x 512 threads (8 waves). Block owns rows [b*16, b*16+16).
// Operand swap: A = weights (M = out-channels), B = activations (N = batch rows).
// D: outc = (lane>>4)*4 + reg, batch = lane&15  ->  packed 8B epilogue writes.
// Register discipline (the round-3 lesson): at most TWO weight sets in flight at
// any point; node loop pinned to unroll 1 so live ranges don't multiply.
// This structure measured 1463 us (r4) and survived 7 attack vectors (r5-r10)
// without improvement — it sits at the per-CU unique-data L2->L1 stream ceiling
// (~42-45 B/cyc: 240KB/update ≈ 5.5K cyc ≈ measured).
__global__ __launch_bounds__(512, 2) void recur_kernel(
    const float* __restrict__ x,
    const __hip_bfloat16* __restrict__ p1, const float* __restrict__ bf1,
    const __hip_bfloat16* __restrict__ p2, const float* __restrict__ bf2,
    const __hip_bfloat16* __restrict__ p3, const float* __restrict__ bf3,
    float* __restrict__ feat_out) {
  __shared__ __align__(16) __hip_bfloat16 inp_s[BM][INP_STRIDE];
  __shared__ __align__(16) __hip_bfloat16 h1_s[BM][H_STRIDE];
  __shared__ __align__(16) __hip_bfloat16 h2_s[BM][H_STRIDE];

  const int tid = threadIdx.x;
  const int lane = tid & 63;
  const int w = tid >> 6;          // wave 0..7
  const int g = lane >> 4;         // k-group (loads) / outc-subgroup (epilogue)
  const int c16 = lane & 15;       // batch row
  const int ct0 = 2 * w, ct1 = 2 * w + 1;
  const int r0 = blockIdx.x * BM;

  const bfrag* Pf1 = (const bfrag*)p1;
  const bfrag* Pf2 = (const bfrag*)p2;
  const bfrag* Pf3 = (const bfrag*)p3;

  // x-staging role: threads 128..207 (waves 2-3) own one (row, node) pair
  const bool xact = (tid >= 128 && tid < 128 + BM * N_NODES);
  const int xr = (tid - 128) / N_NODES, xn = (tid - 128) % N_NODES;

  // zero state + pads
  for (int idx = tid; idx < BM * INP_STRIDE; idx += 512)
    ((__hip_bfloat16*)inp_s)[idx] = tobf(0.f);
  __syncthreads();
  // x_0 -> cols 160..164
  if (tid < BM * N_NODES) {
    int r = tid / N_NODES, n = tid % N_NODES;
    inp_s[r][160 + n] = tobf(x[(size_t)(r0 + r) * (N_NODES * T_STEPS) + n * T_STEPS]);
  }
  __syncthreads();

  // preload node-0 L1 weights (48 VGPRs, persistent across phases)
  bfrag wL1[2][L1_KT];
#pragma unroll
  for (int kt = 0; kt < L1_KT; ++kt) {
    wL1[0][kt] = Pf1[(kt * L1_CT + ct0) * 64 + lane];
    wL1[1][kt] = Pf1[(kt * L1_CT + ct1) * 64 + lane];
  }

#pragma unroll 1
  for (int t = 0; t < T_STEPS; ++t) {
#pragma unroll 1
    for (int i = 0; i < N_NODES; ++i) {
      const int inext = (i + 1 == N_NODES) ? 0 : i + 1;

      // ================= PHASE A: layer 1 [16 outc-tiles x K192] =================
      {
        // prefetch this node's L2 weights (consumed in PHASE B; drained at barrier)
        bfrag w2[2][L2_KT];
        {
          const bfrag* P = Pf2 + (size_t)i * L2_FRAGS * 64;
#pragma unroll
          for (int kt = 0; kt < L2_KT; ++kt) {
            w2[0][kt] = P[(kt * L2_CT + ct0) * 64 + lane];
            w2[1][kt] = P[(kt * L2_CT + ct1) * 64 + lane];
          }
        }
        // bias hoisted to phase top (lands during MFMA chain)
        float4 bia0 = *(const float4*)&bf1[i * F1 + ct0 * 16 + 4 * g];
        float4 bia1 = *(const float4*)&bf1[i * F1 + ct1 * 16 + 4 * g];

        bfrag a[L1_KT];
#pragma unroll
        for (int kt = 0; kt < L1_KT; ++kt)
          a[kt] = *(const bfrag*)&inp_s[c16][kt * 32 + g * 8];
        f32x4 acc0 = {0.f,0.f,0.f,0.f}, acc1 = {0.f,0.f,0.f,0.f};
        f32x4 acc0b = {0.f,0.f,0.f,0.f}, acc1b = {0.f,0.f,0.f,0.f};
#pragma unroll
        for (int kt = 0; kt < 3; ++kt) {
          acc0  = MFMA16(wL1[0][kt],     a[kt],     acc0,  0, 0, 0);
          acc1  = MFMA16(wL1[1][kt],     a[kt],     acc1,  0, 0, 0);
          acc0b = MFMA16(wL1[0][kt + 3], a[kt + 3], acc0b, 0, 0, 0);
          acc1b = MFMA16(wL1[1][kt + 3], a[kt + 3], acc1b, 0, 0, 0);
        }
        acc0 += acc0b; acc1 += acc1b;
        relu_pack_store(&h1_s[c16][ct0 * 16 + 4 * g], acc0, bia0);
        relu_pack_store(&h1_s[c16][ct1 * 16 + 4 * g], acc1, bia1);
        __syncthreads();

        // ================= PHASE B: layer 2 [16 outc-tiles x K256] =================
        // prefetch L3 weights (waves 0-1 only; consumed in PHASE C)
        bfrag w3[L3_KT];
        if (w < 2) {
          const bfrag* P = Pf3 + (size_t)i * L3_FRAGS * 64;
#pragma unroll
          for (int kt = 0; kt < L3_KT; ++kt)
            w3[kt] = P[(kt * L3_CT + w) * 64 + lane];
        }
        float4 bib0 = *(const float4*)&bf2[i * F2 + ct0 * 16 + 4 * g];
        float4 bib1 = *(const float4*)&bf2[i * F2 + ct1 * 16 + 4 * g];

        {
          bfrag ab[L2_KT];
#pragma unroll
          for (int kt = 0; kt < L2_KT; ++kt)
            ab[kt] = *(const bfrag*)&h1_s[c16][kt * 32 + g * 8];
          f32x4 bcc0 = {0.f,0.f,0.f,0.f}, bcc1 = {0.f,0.f,0.f,0.f};
          f32x4 bcc0b = {0.f,0.f,0.f,0.f}, bcc1b = {0.f,0.f,0.f,0.f};
#pragma unroll
          for (int kt = 0; kt < 4; ++kt) {
            bcc0  = MFMA16(w2[0][kt],     ab[kt],     bcc0,  0, 0, 0);
            bcc1  = MFMA16(w2[1][kt],     ab[kt],     bcc1,  0, 0, 0);
            bcc0b = MFMA16(w2[0][kt + 4], ab[kt + 4], bcc0b, 0, 0, 0);
            bcc1b = MFMA16(w2[1][kt + 4], ab[kt + 4], bcc1b, 0, 0, 0);
          }
          bcc0 += bcc0b; bcc1 += bcc1b;
          relu_pack_store(&h2_s[c16][ct0 * 16 + 4 * g], bcc0, bib0);
          relu_pack_store(&h2_s[c16][ct1 * 16 + 4 * g], bcc1, bib1);
        }
        __syncthreads();

        // ================= PHASE C: layer 3 -> state; prefetch next L1 =================
        // ALL waves issue next node's L1 loads first (overlap L3 compute / barrier)
        bfrag w1n[2][L1_KT];
        {
          const bfrag* P = Pf1 + (size_t)inext * L1_FRAGS * 64;
#pragma unroll
          for (int kt = 0; kt < L1_KT; ++kt) {
            w1n[0][kt] = P[(kt * L1_CT + ct0) * 64 + lane];
            w1n[1][kt] = P[(kt * L1_CT + ct1) * 64 + lane];
          }
        }
        if (w < 2) {
          bfrag ac[L3_KT];
#pragma unroll
          for (int kt = 0; kt < L3_KT; ++kt)
            ac[kt] = *(const bfrag*)&h2_s[c16][kt * 32 + g * 8];
          f32x4 ccc = {0.f,0.f,0.f,0.f}, cccb = {0.f,0.f,0.f,0.f};
#pragma unroll
          for (int kt = 0; kt < 4; ++kt) {
            ccc  = MFMA16(w3[kt],     ac[kt],     ccc,  0, 0, 0);
            cccb = MFMA16(w3[kt + 4], ac[kt + 4], cccb, 0, 0, 0);
          }
          ccc += cccb;
          const int sc = i * FML + w * 16 + 4 * g;   // state col base (0..159)
          float4 bic = *(const float4*)&bf3[sc];
          union { ushort4 v; __hip_bfloat16 h[4]; } u;
          float vs[4];
#pragma unroll
          for (int e = 0; e < 4; ++e) {
            vs[e] = fmaxf(ccc[e] + ((const float*)&bic)[e], 0.f);
            u.h[e] = tobf(vs[e]);
          }
          *reinterpret_cast<ushort4*>(&inp_s[c16][sc]) = u.v;   // Gauss-Seidel update
          if (t == T_STEPS - 1) {
#pragma unroll
            for (int e = 0; e < 4; ++e)
              feat_out[(size_t)(r0 + c16) * IN_F + 5 + sc + e] = vs[e];  // fp32 state for head
          }
        } else if (i == N_NODES - 1 && xact && t + 1 < T_STEPS) {
          // idle waves stage x_{t+1}; all A-phase reads of x cols are past
          float xv = x[(size_t)(r0 + xr) * (N_NODES * T_STEPS) + xn * T_STEPS + (t + 1)];
          inp_s[xr][160 + xn] = tobf(xv);
        }
        __syncthreads();

        // rotate next-node L1 weights in
#pragma unroll
        for (int kt = 0; kt < L1_KT; ++kt) {
          wL1[0][kt] = w1n[0][kt];
          wL1[1][kt] = w1n[1][kt];
        }
      }
    }
  }

  // feat x-part (fp32, exact)
  if (tid < BM * N_NODES) {
    int r = tid / N_NODES, n = tid % N_NODES;
    feat_out[(size_t)(r0 + r) * IN_F + n] =
        x[(size_t)(r0 + r) * (N_NODES * T_STEPS) + n * T_STEPS + (T_STEPS - 1)];
  }
}

// ---------------- Kernel 2: head layer 1 (feat @ Wo1 + bo1, ReLU) ----------------
__global__ __launch_bounds__(256) void head1_kernel(
    const float* __restrict__ feat, const float* __restrict__ Wo1,
    const float* __restrict__ bo1, float* __restrict__ H) {
  __shared__ __align__(16) float f[BMH][168];
  const int tid = threadIdx.x;
  const int r0 = blockIdx.x * BMH;
  for (int idx = tid; idx < BMH * 168; idx += 256) {
    int r = idx / 168, c = idx % 168;
    f[r][c] = (c < IN_F) ? feat[(size_t)(r0 + r) * IN_F + c] : 0.f;
  }
  __syncthreads();
  const int c0 = tid, c1 = tid + 256;
  float acc0[BMH], acc1[BMH];
#pragma unroll
  for (int r = 0; r < BMH; ++r) { acc0[r] = 0.f; acc1[r] = 0.f; }
  int k = 0;
  for (; k + 3 < IN_F; k += 4) {
    float w00 = Wo1[(k + 0) * F3 + c0], w01 = Wo1[(k + 0) * F3 + c1];
    float w10 = Wo1[(k + 1) * F3 + c0], w11 = Wo1[(k + 1) * F3 + c1];
    float w20 = Wo1[(k + 2) * F3 + c0], w21 = Wo1[(k + 2) * F3 + c1];
    float w30 = Wo1[(k + 3) * F3 + c0], w31 = Wo1[(k + 3) * F3 + c1];
#pragma unroll
    for (int r = 0; r < BMH; ++r) {
      float4 v = *reinterpret_cast<const float4*>(&f[r][k]);
      acc0[r] = fmaf(v.x, w00, acc0[r]); acc1[r] = fmaf(v.x, w01, acc1[r]);
      acc0[r] = fmaf(v.y, w10, acc0[r]); acc1[r] = fmaf(v.y, w11, acc1[r]);
      acc0[r] = fmaf(v.z, w20, acc0[r]); acc1[r] = fmaf(v.z, w21, acc1[r]);
      acc0[r] = fmaf(v.w, w30, acc0[r]); acc1[r] = fmaf(v.w, w31, acc1[r]);
    }
  }
  {
    float w0 = Wo1[164 * F3 + c0], w1 = Wo1[164 * F3 + c1];
#pragma unroll
    for (int r = 0; r < BMH; ++r) {
      acc0[r] = fmaf(f[r][164], w0, acc0[r]);
      acc1[r] = fmaf(f[r][164], w1, acc1[r]);
    }
  }
  float b0 = bo1[c0], b1 = bo1[c1];
#pragma unroll
  for (int r = 0; r < BMH; ++r) {
    H[(size_t)(r0 + r) * F3 + c0] = fmaxf(acc0[r] + b0, 0.f);
    H[(size_t)(r0 + r) * F3 + c1] = fmaxf(acc1[r] + b1, 0.f);
  }
}

// ---------------- Kernel 3: BN stats -> per-column scale/shift ----------------
__global__ __launch_bounds__(256) void bn_stats_kernel(
    const float* __restrict__ H, const float* __restrict__ gamma,
    const float* __restrict__ beta, float* __restrict__ ab) {
  const int c = blockIdx.x;
  const int tid = threadIdx.x;
  float sm = 0.f, q = 0.f;
  for (int r = tid; r < B_TOT; r += 256) {
    float v = H[(size_t)r * F3 + c];
    sm += v; q += v * v;
  }
  __shared__ float ls[256], lq[256];
  ls[tid] = sm; lq[tid] = q;
  __syncthreads();
  for (int off = 128; off; off >>= 1) {
    if (tid < off) { ls[tid] += ls[tid + off]; lq[tid] += lq[tid + off]; }
    __syncthreads();
  }
  if (tid == 0) {
    float mu = ls[0] * (1.f / B_TOT);
    float var = lq[0] * (1.f / B_TOT) - mu * mu;
    float inv = rsqrtf(var + 1e-5f);
    float a = gamma[c] * inv;
    ab[c] = a;
    ab[F3 + c] = beta[c] - mu * a;
  }
}

// ---------------- Kernel 4: logits + softmax (1 wave per row) ----------------
__global__ __launch_bounds__(256) void out_kernel(
    const float* __restrict__ H, const float* __restrict__ ab,
    const float* __restrict__ Wo2, const float* __restrict__ bo2,
    float* __restrict__ out) {
  const int wid = threadIdx.x >> 6, lane = threadIdx.x & 63;
  const int r = blockIdx.x * 4 + wid;
  float acc[NCLS];
#pragma unroll
  for (int j = 0; j < NCLS; ++j) acc[j] = 0.f;
  for (int k = lane; k < F3; k += 64) {
    float hv = H[(size_t)r * F3 + k] * ab[k] + ab[F3 + k];
#pragma unroll
    for (int j = 0; j < NCLS; ++j) acc[j] = fmaf(hv, Wo2[k * NCLS + j], acc[j]);
  }
#pragma unroll
  for (int j = 0; j < NCLS; ++j)
    for (int off = 32; off; off >>= 1) acc[j] += __shfl_xor(acc[j], off);
  if (lane == 0) {
    float lg[NCLS], mx = -1e30f;
#pragma unroll
    for (int j = 0; j < NCLS; ++j) { lg[j] = acc[j] + bo2[j]; mx = fmaxf(mx, lg[j]); }
    float sum = 0.f;
#pragma unroll
    for (int j = 0; j < NCLS; ++j) { lg[j] = __expf(lg[j] - mx); sum += lg[j]; }
    float inv = 1.f / sum;
#pragma unroll
    for (int j = 0; j < NCLS; ++j) out[(size_t)r * NCLS + j] = lg[j] * inv;
  }
}

extern "C" void kernel_launch(void* const* d_in, const int* in_sizes, int n_in,
                              void* d_out, int out_size, void* d_ws, size_t ws_size,
                              hipStream_t stream) {
  const float* x   = (const float*)d_in[0];
  const float* Wf1 = (const float*)d_in[1];
  const float* bf1 = (const float*)d_in[2];
  const float* Wf2 = (const float*)d_in[3];
  const float* bf2 = (const float*)d_in[4];
  const float* Wf3 = (const float*)d_in[5];
  const float* bf3 = (const float*)d_in[6];
  const float* Wo1 = (const float*)d_in[7];
  const float* bo1 = (const float*)d_in[8];
  const float* gamma = (const float*)d_in[9];
  const float* beta  = (const float*)d_in[10];
  const float* Wo2 = (const float*)d_in[11];
  const float* bo2 = (const float*)d_in[12];
  float* out = (float*)d_out;

  char* ws = (char*)d_ws;
  size_t off = 0;
  __hip_bfloat16* p1 = (__hip_bfloat16*)(ws + off); off += (size_t)N_NODES * L1_FRAGS * 64 * 8 * 2;
  __hip_bfloat16* p2 = (__hip_bfloat16*)(ws + off); off += (size_t)N_NODES * L2_FRAGS * 64 * 8 * 2;
  __hip_bfloat16* p3 = (__hip_bfloat16*)(ws + off); off += (size_t)N_NODES * L3_FRAGS * 64 * 8 * 2;
  float* feat = (float*)(ws + off); off += (size_t)B_TOT * IN_F * 4;
  float* H    = (float*)(ws + off); off += (size_t)B_TOT * F3 * 4;
  float* ab   = (float*)(ws + off); off += 2 * F3 * 4;

  pack_weights<<<300, 256, 0, stream>>>(Wf1, Wf2, Wf3, p1, p2, p3);
  recur_kernel<<<B_TOT / BM, 512, 0, stream>>>(x, p1, bf1, p2, bf2, p3, bf3, feat);
  head1_kernel<<<B_TOT / BMH, 256, 0, stream>>>(feat, Wo1, bo1, H);
  bn_stats_kernel<<<F3, 256, 0, stream>>>(H, gamma, beta, ab);
  out_kernel<<<B_TOT / 4, 256, 0, stream>>>(H, ab, Wo2, bo2, out);
}